// Round 2
// baseline (108.875 us; speedup 1.0000x reference)
//
#include <hip/hip_runtime.h>

#define G 64
#define BLOCK 256
#define NBLOCKS 1280   // 5 blocks/CU * 256 CUs: all resident (32KB LDS -> 5/CU cap)

// Native clang vector types: __builtin_nontemporal_load requires these
// (HIP_vector_type float4/int4 are structs and are rejected).
typedef float vfloat4 __attribute__((ext_vector_type(4)));
typedef int   vint4   __attribute__((ext_vector_type(4)));

// Evaluate one point: Catmull-Rom 4x4 weighted gather from LDS table, return squared error.
__device__ __forceinline__ float eval_point(
    float cx, float cy, int ix, int iy, float t1x, float t1y,
    const float2* __restrict__ lds_cp)
{
    const float x = cx - floorf(cx);
    const float y = cy - floorf(cy);

    float wxv[4], wyv[4];
    wxv[0] = ((-0.5f * x + 1.0f) * x - 0.5f) * x;
    wxv[1] = (1.5f * x - 2.5f) * x * x + 1.0f;
    wxv[2] = ((-1.5f * x + 2.0f) * x + 0.5f) * x;
    wxv[3] = (0.5f * x - 0.5f) * x * x;
    wyv[0] = ((-0.5f * y + 1.0f) * y - 0.5f) * y;
    wyv[1] = (1.5f * y - 2.5f) * y * y + 1.0f;
    wyv[2] = ((-1.5f * y + 2.0f) * y + 0.5f) * y;
    wyv[3] = (0.5f * y - 0.5f) * y * y;

    const int base = (ix - 1) * G + (iy - 1);
    float s0 = 0.0f, s1 = 0.0f;
    #pragma unroll
    for (int i = 0; i < 4; ++i) {
        float r0 = 0.0f, r1 = 0.0f;
        #pragma unroll
        for (int j = 0; j < 4; ++j) {
            const float2 q = lds_cp[base + i * G + j];
            r0 = fmaf(wyv[j], q.x, r0);
            r1 = fmaf(wyv[j], q.y, r1);
        }
        s0 = fmaf(wxv[i], r0, s0);
        s1 = fmaf(wxv[i], r1, s1);
    }

    const float d0 = t1x - s0;
    const float d1 = t1y - s1;
    return fmaf(d0, d0, d1 * d1);
}

__global__ __launch_bounds__(BLOCK) void crs_kernel(
    const vfloat4* __restrict__ ch1,   // viewed as pairs of float2
    const vfloat4* __restrict__ ch2,
    const float4* __restrict__ cp,     // CP_locs viewed as float4 (G*G/2 of them)
    const vint4*  __restrict__ idx,    // viewed as pairs of int2
    float* __restrict__ out, int n)
{
    __shared__ float2 lds_cp[G * G];     // 32 KB
    __shared__ float  wave_sums[BLOCK / 64];

    // Stage CP_locs -> LDS, vectorized 16B: 2048 float4s, 8 per thread.
    // (Normal, cacheable loads: the table is re-read by all 1280 blocks and wants L2.)
    {
        float4* lds4 = (float4*)lds_cp;
        #pragma unroll
        for (int i = threadIdx.x; i < (G * G) / 2; i += BLOCK)
            lds4[i] = cp[i];
    }
    __syncthreads();

    float acc = 0.0f;
    const int npairs = n >> 1;
    const int stride = NBLOCKS * BLOCK;

    // 2 points per thread: 16B/lane loads on all three read-once streams.
    // Nontemporal: don't let 48MB of streams evict the CP table from L2.
    for (int t = blockIdx.x * BLOCK + threadIdx.x; t < npairs; t += stride) {
        const vfloat4 c2 = __builtin_nontemporal_load(&ch2[t]);
        const vint4   ij = __builtin_nontemporal_load(&idx[t]);
        const vfloat4 c1 = __builtin_nontemporal_load(&ch1[t]);

        acc += eval_point(c2.x, c2.y, ij.x, ij.y, c1.x, c1.y, lds_cp);
        acc += eval_point(c2.z, c2.w, ij.z, ij.w, c1.z, c1.w, lds_cp);
    }

    // Odd-N tail (N=2M is even; kept for generality).
    if ((n & 1) && blockIdx.x == 0 && threadIdx.x == 0) {
        const float2* ch1s = (const float2*)ch1;
        const float2* ch2s = (const float2*)ch2;
        const int2*   idxs = (const int2*)idx;
        const float2 c2 = ch2s[n - 1];
        const int2   ij = idxs[n - 1];
        const float2 c1 = ch1s[n - 1];
        acc += eval_point(c2.x, c2.y, ij.x, ij.y, c1.x, c1.y, lds_cp);
    }

    // Wave-64 butterfly reduce, then cross-wave via LDS, one atomic per block.
    #pragma unroll
    for (int off = 32; off > 0; off >>= 1)
        acc += __shfl_down(acc, off, 64);

    const int lane = threadIdx.x & 63;
    const int wave = threadIdx.x >> 6;
    if (lane == 0) wave_sums[wave] = acc;
    __syncthreads();
    if (threadIdx.x == 0) {
        float s = 0.0f;
        #pragma unroll
        for (int w = 0; w < BLOCK / 64; ++w) s += wave_sums[w];
        atomicAdd(out, s);
    }
}

extern "C" void kernel_launch(void* const* d_in, const int* in_sizes, int n_in,
                              void* d_out, int out_size, void* d_ws, size_t ws_size,
                              hipStream_t stream) {
    const vfloat4* ch1 = (const vfloat4*)d_in[0];
    const vfloat4* ch2 = (const vfloat4*)d_in[1];
    const float4*  cp  = (const float4*)d_in[2];   // CP_locs (G,G,2) f32
    const vint4*   idx = (const vint4*)d_in[3];
    float* out = (float*)d_out;
    const int n = in_sizes[0] / 2;   // N points

    // d_out is poisoned to 0xAA before every timed launch; zero it on-stream.
    hipMemsetAsync(out, 0, sizeof(float), stream);
    crs_kernel<<<NBLOCKS, BLOCK, 0, stream>>>(ch1, ch2, cp, idx, out, n);
}